// Round 1
// baseline (146.425 us; speedup 1.0000x reference)
//
#include <hip/hip_runtime.h>

#define EPS 1e-5f
#define TS 64
#define KT 32
#define PAD 4

// ---------------- prep: BN-folded weights + offsets ----------------
__global__ __launch_bounds__(256) void prep_kernel(
    const int* __restrict__ ld,
    const float* __restrict__ Wl, const float* __restrict__ bl,
    const float* __restrict__ gl, const float* __restrict__ betal,
    const float* __restrict__ ml, const float* __restrict__ vl,
    const float* __restrict__ W1, const float* __restrict__ b1,
    const float* __restrict__ g1, const float* __restrict__ beta1,
    const float* __restrict__ m1, const float* __restrict__ v1,
    const float* __restrict__ W2, const float* __restrict__ b2,
    const float* __restrict__ g2, const float* __restrict__ beta2,
    const float* __restrict__ m2, const float* __restrict__ v2,
    int* __restrict__ offs, float* __restrict__ c1, float* __restrict__ cf,
    float* __restrict__ W1s, float* __restrict__ Wc)
{
    int t = threadIdx.x;
    int gsize = gridDim.x * blockDim.x;
    int gt = blockIdx.x * blockDim.x + t;
    if (blockIdx.x == 0) {
        if (t < 64) {
            int s = 0;
            for (int i = 0; i < t; ++i) s += ld[i];
            offs[t] = s;
        }
        if (t < 128) {
            float s1 = g1[t] / sqrtf(v1[t] + EPS);
            c1[t] = (b1[t] - m1[t]) * s1 + beta1[t];
        }
        if (t < 256) {
            float s2 = g2[t] / sqrtf(v2[t] + EPS);
            float sl = gl[t] / sqrtf(vl[t] + EPS);
            cf[t] = (b2[t] - m2[t]) * s2 + beta2[t] + (bl[t] - ml[t]) * sl + betal[t];
        }
    }
    for (int idx = gt; idx < 128 * 128; idx += gsize) {
        int n = idx >> 7;
        float s1 = g1[n] / sqrtf(v1[n] + EPS);
        W1s[idx] = W1[idx] * s1;
    }
    for (int idx = gt; idx < 256 * 256; idx += gsize) {
        int n = idx >> 8, k = idx & 255;
        float v;
        if (k < 128) {
            float s2 = g2[n] / sqrtf(v2[n] + EPS);
            v = W2[n * 128 + k] * s2;
        } else {
            float sl = gl[n] / sqrtf(vl[n] + EPS);
            v = Wl[n * 128 + (k - 128)] * sl;
        }
        Wc[idx] = v;
    }
}

// ---------------- ragged block-diagonal aggregation: C = am[g][:l,:l] @ X_block ----------------
__global__ __launch_bounds__(256) void agg_kernel(
    const float* __restrict__ am, const float* __restrict__ X,
    const int* __restrict__ ld, const int* __restrict__ offs,
    float* __restrict__ C)
{
    int g = blockIdx.y;
    int l = ld[g];
    int rt = blockIdx.x >> 1;   // row tile (0..7)
    int ct = blockIdx.x & 1;    // col tile (0..1), N=128
    if (rt * TS >= l) return;
    int off = offs[g];
    const float* A = am + (size_t)g * 512 * 512;
    int r0 = rt * TS, n0 = ct * TS;

    __shared__ __align__(16) float As[KT][TS + PAD];
    __shared__ __align__(16) float Bs[KT][TS + PAD];

    int tx = threadIdx.x, ty = threadIdx.y;
    int tid = ty * 16 + tx;
    float acc[4][4] = {};

    int nk = (l + KT - 1) / KT;
    for (int kt = 0; kt < nk; ++kt) {
        int k0 = kt * KT;
        // stage A rows r0..r0+63, cols k0..k0+31 -> As[kk][r] (transposed)
        {
            int r = tid >> 3;
            int k4 = (tid & 7) * 4;
            #pragma unroll
            for (int h = 0; h < 2; ++h) {
                int rr = r + h * 32;
                float4 v = make_float4(0.f, 0.f, 0.f, 0.f);
                if (r0 + rr < l && k0 + k4 < l)
                    v = *(const float4*)(A + (size_t)(r0 + rr) * 512 + k0 + k4);
                As[k4 + 0][rr] = v.x; As[k4 + 1][rr] = v.y;
                As[k4 + 2][rr] = v.z; As[k4 + 3][rr] = v.w;
            }
        }
        // stage B rows (nodes) k0..k0+31, cols n0..n0+63 -> Bs[kk][n]
        {
            int k = tid >> 4;
            int n4 = (tid & 15) * 4;
            #pragma unroll
            for (int h = 0; h < 2; ++h) {
                int kk = k + h * 16;
                float4 v = make_float4(0.f, 0.f, 0.f, 0.f);
                if (k0 + kk < l)
                    v = *(const float4*)(X + (size_t)(off + k0 + kk) * 128 + n0 + n4);
                *(float4*)&Bs[kk][n4] = v;
            }
        }
        __syncthreads();
        #pragma unroll
        for (int kk = 0; kk < KT; ++kk) {
            float4 a4 = *(const float4*)&As[kk][ty * 4];
            float4 b4 = *(const float4*)&Bs[kk][tx * 4];
            float av[4] = {a4.x, a4.y, a4.z, a4.w};
            float bv[4] = {b4.x, b4.y, b4.z, b4.w};
            #pragma unroll
            for (int i = 0; i < 4; ++i)
                #pragma unroll
                for (int j = 0; j < 4; ++j)
                    acc[i][j] = fmaf(av[i], bv[j], acc[i][j]);
        }
        __syncthreads();
    }
    #pragma unroll
    for (int i = 0; i < 4; ++i) {
        int r = r0 + ty * 4 + i;
        if (r < l) {
            float4 v = make_float4(acc[i][0], acc[i][1], acc[i][2], acc[i][3]);
            *(float4*)(C + (size_t)(off + r) * 128 + n0 + tx * 4) = v;
        }
    }
}

// ---------------- linear: C = A @ W^T + bias, optional K-split A and activation ----------------
// EPI: 0 none, 1 relu, 2 leaky(0.01)
template<int KTOT, bool SPLIT, int EPI>
__global__ __launch_bounds__(256) void lin_kernel(
    const float* __restrict__ A0, const float* __restrict__ A1,
    const float* __restrict__ W, const float* __restrict__ bias,
    float* __restrict__ C, int N)
{
    int m0 = blockIdx.x * TS;
    int n0 = blockIdx.y * TS;

    __shared__ __align__(16) float As[KT][TS + PAD];
    __shared__ __align__(16) float Bs[KT][TS + PAD];

    int tx = threadIdx.x, ty = threadIdx.y;
    int tid = ty * 16 + tx;
    float acc[4][4] = {};

    #pragma unroll
    for (int kt = 0; kt < KTOT / KT; ++kt) {
        int k0 = kt * KT;
        const float* Asrc = A0;
        int kloc = k0;
        if (SPLIT && k0 >= 128) { Asrc = A1; kloc = k0 - 128; }
        {
            int r = tid >> 3;
            int k4 = (tid & 7) * 4;
            #pragma unroll
            for (int h = 0; h < 2; ++h) {
                int rr = r + h * 32;
                float4 v = *(const float4*)(Asrc + (size_t)(m0 + rr) * 128 + kloc + k4);
                As[k4 + 0][rr] = v.x; As[k4 + 1][rr] = v.y;
                As[k4 + 2][rr] = v.z; As[k4 + 3][rr] = v.w;
            }
        }
        {
            int r = tid >> 3;
            int k4 = (tid & 7) * 4;
            #pragma unroll
            for (int h = 0; h < 2; ++h) {
                int rr = r + h * 32;
                float4 v = *(const float4*)(W + (size_t)(n0 + rr) * KTOT + k0 + k4);
                Bs[k4 + 0][rr] = v.x; Bs[k4 + 1][rr] = v.y;
                Bs[k4 + 2][rr] = v.z; Bs[k4 + 3][rr] = v.w;
            }
        }
        __syncthreads();
        #pragma unroll
        for (int kk = 0; kk < KT; ++kk) {
            float4 a4 = *(const float4*)&As[kk][ty * 4];
            float4 b4 = *(const float4*)&Bs[kk][tx * 4];
            float av[4] = {a4.x, a4.y, a4.z, a4.w};
            float bv[4] = {b4.x, b4.y, b4.z, b4.w};
            #pragma unroll
            for (int i = 0; i < 4; ++i)
                #pragma unroll
                for (int j = 0; j < 4; ++j)
                    acc[i][j] = fmaf(av[i], bv[j], acc[i][j]);
        }
        __syncthreads();
    }
    float4 bz = *(const float4*)(bias + n0 + tx * 4);
    float bv[4] = {bz.x, bz.y, bz.z, bz.w};
    #pragma unroll
    for (int i = 0; i < 4; ++i) {
        int m = m0 + ty * 4 + i;
        float y[4];
        #pragma unroll
        for (int j = 0; j < 4; ++j) {
            float v = acc[i][j] + bv[j];
            if (EPI == 1) v = v > 0.f ? v : 0.f;
            if (EPI == 2) v = v > 0.f ? v : 0.01f * v;
            y[j] = v;
        }
        *(float4*)(C + (size_t)m * N + n0 + tx * 4) =
            make_float4(y[0], y[1], y[2], y[3]);
    }
}

extern "C" void kernel_launch(void* const* d_in, const int* in_sizes, int n_in,
                              void* d_out, int out_size, void* d_ws, size_t ws_size,
                              hipStream_t stream) {
    const float* x     = (const float*)d_in[0];
    const int*   ld    = (const int*)d_in[1];
    const float* am    = (const float*)d_in[2];
    const float* Wl    = (const float*)d_in[3];
    const float* bl    = (const float*)d_in[4];
    const float* gl    = (const float*)d_in[5];
    const float* betal = (const float*)d_in[6];
    const float* ml    = (const float*)d_in[7];
    const float* vl    = (const float*)d_in[8];
    const float* W1    = (const float*)d_in[9];
    const float* b1    = (const float*)d_in[10];
    const float* g1    = (const float*)d_in[11];
    const float* beta1 = (const float*)d_in[12];
    const float* m1    = (const float*)d_in[13];
    const float* v1    = (const float*)d_in[14];
    const float* W2    = (const float*)d_in[15];
    const float* b2    = (const float*)d_in[16];
    const float* g2    = (const float*)d_in[17];
    const float* beta2 = (const float*)d_in[18];
    const float* m2    = (const float*)d_in[19];
    const float* v2    = (const float*)d_in[20];
    float* out = (float*)d_out;

    int M = in_sizes[0] / 128;   // 16384

    char* w = (char*)d_ws;
    int*   offs = (int*)w;                                  // 64 ints
    float* c1   = (float*)(w + 512);                        // 128 f
    float* cf   = (float*)(w + 1024);                       // 256 f
    float* W1s  = (float*)(w + 2048);                       // 128*128 f
    float* Wc   = (float*)(w + 2048 + 65536);               // 256*256 f
    float* buf1 = (float*)(w + 2048 + 65536 + 262144);      // M*128 f
    float* buf2 = (float*)(w + 2048 + 65536 + 262144 + (size_t)M * 128 * 4);

    prep_kernel<<<64, 256, 0, stream>>>(ld,
        Wl, bl, gl, betal, ml, vl,
        W1, b1, g1, beta1, m1, v1,
        W2, b2, g2, beta2, m2, v2,
        offs, c1, cf, W1s, Wc);

    dim3 blk(16, 16);
    // agg1: buf1 = A @ x
    agg_kernel<<<dim3(16, 64), blk, 0, stream>>>(am, x, ld, offs, buf1);
    // lin1: buf2 = relu(buf1 @ W1s^T + c1)
    lin_kernel<128, false, 1><<<dim3(M / TS, 2), blk, 0, stream>>>(
        buf1, nullptr, W1s, c1, buf2, 128);
    // agg2: buf1 = A @ buf2
    agg_kernel<<<dim3(16, 64), blk, 0, stream>>>(am, buf2, ld, offs, buf1);
    // final: out = leaky([buf1 | x] @ Wc^T + cf)
    lin_kernel<256, true, 2><<<dim3(M / TS, 4), blk, 0, stream>>>(
        buf1, x, Wc, cf, out, 256);
}

// Round 3
// 75.781 us; speedup vs baseline: 1.9322x; 1.9322x over previous
//
#include <hip/hip_runtime.h>

#define EPS 1e-5f

typedef __attribute__((ext_vector_type(4))) float f32x4;
typedef __attribute__((ext_vector_type(8))) _Float16 f16x8;
typedef __attribute__((ext_vector_type(4))) _Float16 f16x4;

// ---------------- prep: BN-folded fp16 weights + offsets + biases ----------------
__global__ __launch_bounds__(256) void prep_kernel(
    const int* __restrict__ ld,
    const float* __restrict__ Wl, const float* __restrict__ bl,
    const float* __restrict__ gl, const float* __restrict__ betal,
    const float* __restrict__ ml, const float* __restrict__ vl,
    const float* __restrict__ W1, const float* __restrict__ b1,
    const float* __restrict__ g1, const float* __restrict__ beta1,
    const float* __restrict__ m1, const float* __restrict__ v1,
    const float* __restrict__ W2, const float* __restrict__ b2,
    const float* __restrict__ g2, const float* __restrict__ beta2,
    const float* __restrict__ m2, const float* __restrict__ v2,
    int* __restrict__ offs, float* __restrict__ c1, float* __restrict__ cf,
    _Float16* __restrict__ W1h, _Float16* __restrict__ Wch)
{
    int t = threadIdx.x;
    int gsize = gridDim.x * blockDim.x;
    int gt = blockIdx.x * blockDim.x + t;
    if (blockIdx.x == 0) {
        if (t < 64) {
            int s = 0;
            for (int i = 0; i < t; ++i) s += ld[i];
            offs[t] = s;
        }
        if (t < 128) {
            float s1 = g1[t] * rsqrtf(v1[t] + EPS);
            c1[t] = (b1[t] - m1[t]) * s1 + beta1[t];
        }
        if (t < 256) {
            float s2 = g2[t] * rsqrtf(v2[t] + EPS);
            float sl = gl[t] * rsqrtf(vl[t] + EPS);
            cf[t] = (b2[t] - m2[t]) * s2 + beta2[t] + (bl[t] - ml[t]) * sl + betal[t];
        }
    }
    for (int idx = gt; idx < 128 * 128; idx += gsize) {
        int n = idx >> 7;
        float s1 = g1[n] * rsqrtf(v1[n] + EPS);
        W1h[idx] = (_Float16)(W1[idx] * s1);
    }
    for (int idx = gt; idx < 256 * 256; idx += gsize) {
        int n = idx >> 8, k = idx & 255;
        float v;
        if (k < 128) {
            float s2 = g2[n] * rsqrtf(v2[n] + EPS);
            v = W2[n * 128 + k] * s2;
        } else {
            float sl = gl[n] * rsqrtf(vl[n] + EPS);
            v = Wl[n * 128 + (k - 128)] * sl;
        }
        Wch[idx] = (_Float16)v;
    }
}

// ---------------- transpose+convert: xT[128][M] fp16 from x[M][128] fp32 ----------------
__global__ __launch_bounds__(256) void convxT_kernel(
    const float* __restrict__ x, _Float16* __restrict__ XT, int M)
{
    int m0 = blockIdx.x * 64;
    __shared__ __align__(16) _Float16 Tt[128][80];
    int tid = threadIdx.x;
    #pragma unroll
    for (int p = 0; p < 8; ++p) {
        int idx = tid + p * 256;
        int m = idx >> 5;
        int f = (idx & 31) * 4;
        float4 v = *(const float4*)&x[(size_t)(m0 + m) * 128 + f];
        Tt[f + 0][m] = (_Float16)v.x; Tt[f + 1][m] = (_Float16)v.y;
        Tt[f + 2][m] = (_Float16)v.z; Tt[f + 3][m] = (_Float16)v.w;
    }
    __syncthreads();
    #pragma unroll
    for (int p = 0; p < 4; ++p) {
        int idx = tid + p * 256;   // [0,1024)
        int f = idx >> 3;          // [0,128)
        int m8 = (idx & 7) * 8;    // [0,64) step 8
        uint4 v = *(const uint4*)&Tt[f][m8];
        *(uint4*)&XT[(size_t)f * M + m0 + m8] = v;
    }
}

// ---------------- agg (MFMA, swapped): out[m][n] = sum_k am[m][k] * XT[n][k] ----------------
// assumes l % 64 == 0 (harness lengths are 128/384)
__global__ __launch_bounds__(256) void agg_mfma_kernel(
    const float* __restrict__ am, const _Float16* __restrict__ XT,
    const int* __restrict__ ld, const int* __restrict__ offs,
    _Float16* __restrict__ out, int M)
{
    int g = blockIdx.y;
    int l = ld[g];
    int r0 = blockIdx.x * 64;
    if (r0 >= l) return;
    int off = offs[g];
    const float* A = am + (size_t)g * 512 * 512;

    __shared__ __align__(16) _Float16 As[128][40]; // xT tile: feat x k
    __shared__ __align__(16) _Float16 Bs[64][40];  // am tile: row x k

    int tid = threadIdx.x;
    int lane = tid & 63;
    int w = tid >> 6;
    int l15 = lane & 15;
    int l4 = lane >> 4;

    f32x4 acc[2][4];
    #pragma unroll
    for (int i = 0; i < 2; ++i)
        #pragma unroll
        for (int j = 0; j < 4; ++j)
            acc[i][j] = (f32x4){0.f, 0.f, 0.f, 0.f};

    uint4 pa[2]; float4 pb[2];
    #pragma unroll
    for (int p = 0; p < 2; ++p) {
        int idx = tid + p * 256;
        pa[p] = *(const uint4*)&XT[(size_t)(idx >> 2) * M + off + (idx & 3) * 8];
        pb[p] = *(const float4*)(A + (size_t)(r0 + (idx >> 3)) * 512 + (idx & 7) * 4);
    }

    int nk = l >> 5;
    for (int s = 0; s < nk; ++s) {
        #pragma unroll
        for (int p = 0; p < 2; ++p) {
            int idx = tid + p * 256;
            *(uint4*)&As[idx >> 2][(idx & 3) * 8] = pa[p];
            f16x4 b;
            b[0] = (_Float16)pb[p].x; b[1] = (_Float16)pb[p].y;
            b[2] = (_Float16)pb[p].z; b[3] = (_Float16)pb[p].w;
            *(f16x4*)&Bs[idx >> 3][(idx & 7) * 4] = b;
        }
        if (s + 1 < nk) {
            int k0 = (s + 1) * 32;
            #pragma unroll
            for (int p = 0; p < 2; ++p) {
                int idx = tid + p * 256;
                pa[p] = *(const uint4*)&XT[(size_t)(idx >> 2) * M + off + k0 + (idx & 3) * 8];
                pb[p] = *(const float4*)(A + (size_t)(r0 + (idx >> 3)) * 512 + k0 + (idx & 7) * 4);
            }
        }
        __syncthreads();
        f16x8 a[2], b[4];
        #pragma unroll
        for (int i = 0; i < 2; ++i)
            a[i] = *(const f16x8*)&As[w * 32 + i * 16 + l15][l4 * 8];
        #pragma unroll
        for (int j = 0; j < 4; ++j)
            b[j] = *(const f16x8*)&Bs[j * 16 + l15][l4 * 8];
        #pragma unroll
        for (int i = 0; i < 2; ++i)
            #pragma unroll
            for (int j = 0; j < 4; ++j)
                acc[i][j] = __builtin_amdgcn_mfma_f32_16x16x32_f16(a[i], b[j], acc[i][j], 0, 0, 0);
        __syncthreads();
    }
    // D[row=feat][col=m]: feat n = w*32 + i*16 + l4*4 + r, row m = r0 + j*16 + l15
    #pragma unroll
    for (int i = 0; i < 2; ++i) {
        int n0 = w * 32 + i * 16 + l4 * 4;
        #pragma unroll
        for (int j = 0; j < 4; ++j) {
            int m = r0 + j * 16 + l15;
            f16x4 o;
            o[0] = (_Float16)acc[i][j][0]; o[1] = (_Float16)acc[i][j][1];
            o[2] = (_Float16)acc[i][j][2]; o[3] = (_Float16)acc[i][j][3];
            *(f16x4*)&out[(size_t)(off + m) * 128 + n0] = o;
        }
    }
}

// ---------------- lin1 (MFMA): h2T[n][m] = relu(sum_k A[m][k]*W1h[n][k] + c1[n]) ----------------
__global__ __launch_bounds__(256) void lin1_kernel(
    const _Float16* __restrict__ Ain, const _Float16* __restrict__ Wh,
    const float* __restrict__ bias, _Float16* __restrict__ outT, int M)
{
    int m0 = blockIdx.x * 64;
    __shared__ __align__(16) _Float16 As[64][40];
    __shared__ __align__(16) _Float16 Bs[128][40];

    int tid = threadIdx.x;
    int lane = tid & 63;
    int w = tid >> 6;
    int l15 = lane & 15;
    int l4 = lane >> 4;

    f32x4 acc[4][2];
    #pragma unroll
    for (int i = 0; i < 4; ++i)
        #pragma unroll
        for (int j = 0; j < 2; ++j)
            acc[i][j] = (f32x4){0.f, 0.f, 0.f, 0.f};

    #pragma unroll
    for (int s = 0; s < 4; ++s) {
        int k0 = s * 32;
        {
            int r = tid >> 2, k8 = (tid & 3) * 8;
            *(uint4*)&As[r][k8] = *(const uint4*)&Ain[(size_t)(m0 + r) * 128 + k0 + k8];
        }
        #pragma unroll
        for (int p = 0; p < 2; ++p) {
            int idx = tid + p * 256;
            int f = idx >> 2, k8 = (idx & 3) * 8;
            *(uint4*)&Bs[f][k8] = *(const uint4*)&Wh[(size_t)f * 128 + k0 + k8];
        }
        __syncthreads();
        f16x8 a[4], b[2];
        #pragma unroll
        for (int i = 0; i < 4; ++i)
            a[i] = *(const f16x8*)&As[i * 16 + l15][l4 * 8];
        #pragma unroll
        for (int j = 0; j < 2; ++j)
            b[j] = *(const f16x8*)&Bs[w * 32 + j * 16 + l15][l4 * 8];
        #pragma unroll
        for (int i = 0; i < 4; ++i)
            #pragma unroll
            for (int j = 0; j < 2; ++j)
                acc[i][j] = __builtin_amdgcn_mfma_f32_16x16x32_f16(a[i], b[j], acc[i][j], 0, 0, 0);
        __syncthreads();
    }
    // D: col n = w*32 + j*16 + l15, rows m = m0 + i*16 + l4*4 + r  -> store transposed
    #pragma unroll
    for (int j = 0; j < 2; ++j) {
        int n = w * 32 + j * 16 + l15;
        float bv = bias[n];
        #pragma unroll
        for (int i = 0; i < 4; ++i) {
            f16x4 o;
            #pragma unroll
            for (int r = 0; r < 4; ++r) {
                float v = acc[i][j][r] + bv;
                o[r] = (_Float16)(v > 0.f ? v : 0.f);
            }
            *(f16x4*)&outT[(size_t)n * M + m0 + i * 16 + l4 * 4] = o;
        }
    }
}

// ---------------- final (MFMA): out = leaky([A0 | x] @ Wch^T + cf) fp32 ----------------
__global__ __launch_bounds__(256) void fin_kernel(
    const _Float16* __restrict__ A0, const float* __restrict__ A1,
    const _Float16* __restrict__ Wh, const float* __restrict__ bias,
    float* __restrict__ out, int M)
{
    int m0 = blockIdx.x * 64;
    __shared__ __align__(16) _Float16 As[64][40];
    __shared__ __align__(16) _Float16 Bs[256][40];

    int tid = threadIdx.x;
    int lane = tid & 63;
    int w = tid >> 6;
    int l15 = lane & 15;
    int l4 = lane >> 4;

    f32x4 acc[4][4];
    #pragma unroll
    for (int i = 0; i < 4; ++i)
        #pragma unroll
        for (int j = 0; j < 4; ++j)
            acc[i][j] = (f32x4){0.f, 0.f, 0.f, 0.f};

    #pragma unroll
    for (int s = 0; s < 8; ++s) {
        int k0 = s * 32;
        if (k0 < 128) {
            int r = tid >> 2, k8 = (tid & 3) * 8;
            *(uint4*)&As[r][k8] = *(const uint4*)&A0[(size_t)(m0 + r) * 128 + k0 + k8];
        } else {
            #pragma unroll
            for (int p = 0; p < 2; ++p) {
                int idx = tid + p * 256;
                int r = idx >> 3, k4 = (idx & 7) * 4;
                float4 v = *(const float4*)&A1[(size_t)(m0 + r) * 128 + (k0 - 128) + k4];
                f16x4 h;
                h[0] = (_Float16)v.x; h[1] = (_Float16)v.y;
                h[2] = (_Float16)v.z; h[3] = (_Float16)v.w;
                *(f16x4*)&As[r][k4] = h;
            }
        }
        #pragma unroll
        for (int p = 0; p < 4; ++p) {
            int idx = tid + p * 256;
            int f = idx >> 2, k8 = (idx & 3) * 8;
            *(uint4*)&Bs[f][k8] = *(const uint4*)&Wh[(size_t)f * 256 + k0 + k8];
        }
        __syncthreads();
        f16x8 a[4], b[4];
        #pragma unroll
        for (int i = 0; i < 4; ++i)
            a[i] = *(const f16x8*)&As[i * 16 + l15][l4 * 8];
        #pragma unroll
        for (int j = 0; j < 4; ++j)
            b[j] = *(const f16x8*)&Bs[w * 64 + j * 16 + l15][l4 * 8];
        #pragma unroll
        for (int i = 0; i < 4; ++i)
            #pragma unroll
            for (int j = 0; j < 4; ++j)
                acc[i][j] = __builtin_amdgcn_mfma_f32_16x16x32_f16(a[i], b[j], acc[i][j], 0, 0, 0);
        __syncthreads();
    }
    #pragma unroll
    for (int j = 0; j < 4; ++j) {
        int n = w * 64 + j * 16 + l15;
        float bv = bias[n];
        #pragma unroll
        for (int i = 0; i < 4; ++i) {
            #pragma unroll
            for (int r = 0; r < 4; ++r) {
                int m = m0 + i * 16 + l4 * 4 + r;
                float v = acc[i][j][r] + bv;
                out[(size_t)m * 256 + n] = v > 0.f ? v : 0.01f * v;
            }
        }
    }
}

extern "C" void kernel_launch(void* const* d_in, const int* in_sizes, int n_in,
                              void* d_out, int out_size, void* d_ws, size_t ws_size,
                              hipStream_t stream) {
    const float* x     = (const float*)d_in[0];
    const int*   ld    = (const int*)d_in[1];
    const float* am    = (const float*)d_in[2];
    const float* Wl    = (const float*)d_in[3];
    const float* bl    = (const float*)d_in[4];
    const float* gl    = (const float*)d_in[5];
    const float* betal = (const float*)d_in[6];
    const float* ml    = (const float*)d_in[7];
    const float* vl    = (const float*)d_in[8];
    const float* W1    = (const float*)d_in[9];
    const float* b1    = (const float*)d_in[10];
    const float* g1    = (const float*)d_in[11];
    const float* beta1 = (const float*)d_in[12];
    const float* m1    = (const float*)d_in[13];
    const float* v1    = (const float*)d_in[14];
    const float* W2    = (const float*)d_in[15];
    const float* b2    = (const float*)d_in[16];
    const float* g2    = (const float*)d_in[17];
    const float* beta2 = (const float*)d_in[18];
    const float* m2    = (const float*)d_in[19];
    const float* v2    = (const float*)d_in[20];
    float* out = (float*)d_out;

    int M = in_sizes[0] / 128;   // 16384

    char* w = (char*)d_ws;
    int*   offs = (int*)w;
    float* c1   = (float*)(w + 512);
    float* cf   = (float*)(w + 1024);
    _Float16* W1h  = (_Float16*)(w + 4096);
    _Float16* Wch  = (_Float16*)(w + 4096 + 32768);
    _Float16* xhT  = (_Float16*)(w + 4096 + 32768 + 131072);
    _Float16* buf1h = xhT + (size_t)M * 128;
    _Float16* h2T   = buf1h + (size_t)M * 128;
    _Float16* buf2h = h2T + (size_t)M * 128;

    prep_kernel<<<64, 256, 0, stream>>>(ld,
        Wl, bl, gl, betal, ml, vl,
        W1, b1, g1, beta1, m1, v1,
        W2, b2, g2, beta2, m2, v2,
        offs, c1, cf, W1h, Wch);

    convxT_kernel<<<M / 64, 256, 0, stream>>>(x, xhT, M);

    agg_mfma_kernel<<<dim3(6, 64), 256, 0, stream>>>(am, xhT, ld, offs, buf1h, M);

    lin1_kernel<<<M / 64, 256, 0, stream>>>(buf1h, W1h, c1, h2T, M);

    agg_mfma_kernel<<<dim3(6, 64), 256, 0, stream>>>(am, h2T, ld, offs, buf2h, M);

    fin_kernel<<<M / 64, 256, 0, stream>>>(buf2h, x, Wch, cf, out, M);
}